// Round 1
// baseline (2635.385 us; speedup 1.0000x reference)
//
#include <hip/hip_runtime.h>
#include <math.h>

// ws layout: proj [9][64][1024][64] f32 (144 MiB) then attn [1024][4][1024] f32 (16 MiB)
// requires ws_size >= 160 MiB.
// proj weight order w: 0=q,1=k,2=v,3=q_left,4=k_left,5=q_right,6=k_right,7=q_local,8=k_local
// head layout index: [w][bh=b*16+h][t][d]

// ---------------- GEMM: C[m,n] = sum_k A[m,k]*B[n,k] + bias[n] ----------------
// A: M x K row-major; B: N x K row-major (C = A * B^T). M,N mult of 128, K mult of 16.
template<int MODE>
__global__ __launch_bounds__(256)
void gemm_nt(const float* __restrict__ A, const float* __restrict__ B,
             const float* __restrict__ bias, float* __restrict__ C,
             int M, int N, int K) {
  __shared__ float As[16][132];
  __shared__ float Bs[16][132];
  const int tid = threadIdx.x;
  const int m0 = blockIdx.x * 128;
  const int n0 = blockIdx.y * 128;
  const int tx = tid & 15;       // 0..15
  const int ty = tid >> 4;       // 0..15
  const int lrow = tid & 127;    // 0..127
  const int lk = (tid >> 7) * 8; // 0 or 8

  float acc[8][8];
#pragma unroll
  for (int i = 0; i < 8; ++i)
#pragma unroll
    for (int j = 0; j < 8; ++j) acc[i][j] = 0.f;

  const float* ap = A + (size_t)(m0 + lrow) * K + lk;
  const float* bp = B + (size_t)(n0 + lrow) * K + lk;

  for (int k0 = 0; k0 < K; k0 += 16) {
    float4 av0 = *(const float4*)(ap + k0);
    float4 av1 = *(const float4*)(ap + k0 + 4);
    float4 bv0 = *(const float4*)(bp + k0);
    float4 bv1 = *(const float4*)(bp + k0 + 4);
    As[lk+0][lrow] = av0.x; As[lk+1][lrow] = av0.y;
    As[lk+2][lrow] = av0.z; As[lk+3][lrow] = av0.w;
    As[lk+4][lrow] = av1.x; As[lk+5][lrow] = av1.y;
    As[lk+6][lrow] = av1.z; As[lk+7][lrow] = av1.w;
    Bs[lk+0][lrow] = bv0.x; Bs[lk+1][lrow] = bv0.y;
    Bs[lk+2][lrow] = bv0.z; Bs[lk+3][lrow] = bv0.w;
    Bs[lk+4][lrow] = bv1.x; Bs[lk+5][lrow] = bv1.y;
    Bs[lk+6][lrow] = bv1.z; Bs[lk+7][lrow] = bv1.w;
    __syncthreads();
#pragma unroll
    for (int k = 0; k < 16; ++k) {
      float a[8], b[8];
      *(float4*)&a[0] = *(const float4*)&As[k][ty*4];
      *(float4*)&a[4] = *(const float4*)&As[k][64 + ty*4];
      *(float4*)&b[0] = *(const float4*)&Bs[k][tx*4];
      *(float4*)&b[4] = *(const float4*)&Bs[k][64 + tx*4];
#pragma unroll
      for (int i = 0; i < 8; ++i)
#pragma unroll
        for (int j = 0; j < 8; ++j) acc[i][j] += a[i] * b[j];
    }
    __syncthreads();
  }

#pragma unroll
  for (int i = 0; i < 8; ++i) {
    const int mi = m0 + ((i < 4) ? (ty*4 + i) : (64 + ty*4 + i - 4));
#pragma unroll
    for (int j = 0; j < 8; ++j) {
      const int nj = n0 + ((j < 4) ? (tx*4 + j) : (64 + tx*4 + j - 4));
      float v = acc[i][j] + bias[nj];
      if (MODE == 0) {
        C[(size_t)mi * N + nj] = v;
      } else {
        // scatter into head-major proj layout, scale q (w=0) and q_local (w=7)
        const int w = nj >> 10, h = (nj >> 6) & 15, d = nj & 63;
        if (w == 0 || w == 7) v *= 0.125f;   // hd^-0.5, hd=64
        const int t = mi >> 2, b2 = mi & 3;
        C[(((size_t)w * 64 + (b2 * 16 + h)) * 1024 + t) * 64 + d] = v;
      }
    }
  }
}

// ---------------- fused attention ----------------
// grid (64 bh, 128 row-blocks of R=8), block 512 (8 waves)
__global__ __launch_bounds__(512)
void attn_fused(const float* __restrict__ P, float* __restrict__ attnOut) {
  const int bh = blockIdx.x;
  const int t0 = blockIdx.y * 8;
  const int tid = threadIdx.x;
  const int wave = tid >> 6;
  const int lane = tid & 63;

  const size_t MAT = (size_t)64 * 1024 * 64;
  const size_t bho = (size_t)bh * 1024 * 64;
  const float* Qg  = P + 0*MAT + bho;
  const float* Kg  = P + 1*MAT + bho;
  const float* Vg  = P + 2*MAT + bho;
  const float* Qlf = P + 3*MAT + bho;
  const float* Klf = P + 4*MAT + bho;
  const float* Qrt = P + 5*MAT + bho;
  const float* Krt = P + 6*MAT + bho;
  const float* Qlo = P + 7*MAT + bho;
  const float* Klo = P + 8*MAT + bho;

  __shared__ float sA[8][1024];
  __shared__ float sB[8][1024];

  // scores: Sb[r][s] = sum_d Q[t0+r][d] * K[s][d]; waves partition s, K read once/WG
  auto scores = [&](const float* Qm, const float* Km, float (*Sb)[1024]) {
    const int s0 = wave * 128 + lane;
    const float* k0p = Km + (size_t)s0 * 64;
    const float* k1p = k0p + 64 * 64;
    const float* qb = Qm + (size_t)t0 * 64;
    float acc0[8], acc1[8];
#pragma unroll
    for (int r = 0; r < 8; ++r) { acc0[r] = 0.f; acc1[r] = 0.f; }
#pragma unroll
    for (int d4 = 0; d4 < 16; ++d4) {
      float4 kv0 = *(const float4*)(k0p + d4*4);
      float4 kv1 = *(const float4*)(k1p + d4*4);
#pragma unroll
      for (int r = 0; r < 8; ++r) {
        float4 qv = *(const float4*)(qb + r*64 + d4*4);   // wave-uniform, L1 broadcast
        acc0[r] += kv0.x*qv.x + kv0.y*qv.y + kv0.z*qv.z + kv0.w*qv.w;
        acc1[r] += kv1.x*qv.x + kv1.y*qv.y + kv1.z*qv.z + kv1.w*qv.w;
      }
    }
#pragma unroll
    for (int r = 0; r < 8; ++r) { Sb[r][s0] = acc0[r]; Sb[r][s0 + 64] = acc1[r]; }
  };

  auto softmax_row = [&](float* row) {
    float vals[16];
    float mx = -3.0e38f;
#pragma unroll
    for (int i = 0; i < 16; ++i) { vals[i] = row[i*64 + lane]; mx = fmaxf(mx, vals[i]); }
#pragma unroll
    for (int off = 32; off >= 1; off >>= 1) mx = fmaxf(mx, __shfl_xor(mx, off, 64));
    float sum = 0.f;
#pragma unroll
    for (int i = 0; i < 16; ++i) { vals[i] = expf(vals[i] - mx); sum += vals[i]; }
#pragma unroll
    for (int off = 32; off >= 1; off >>= 1) sum += __shfl_xor(sum, off, 64);
    const float inv = 1.f / sum;
#pragma unroll
    for (int i = 0; i < 16; ++i) row[i*64 + lane] = vals[i] * inv;
  };

  // ---- left/right scores + softmax ----
  scores(Qlf, Klf, sA);
  scores(Qrt, Krt, sB);
  __syncthreads();
  softmax_row(sA[wave]);
  softmax_row(sB[wave]);
  __syncthreads();

  // ---- cumsums -> local_mask (into sA). @triu = fwd cumsum, @triu.T = rev cumsum ----
  {
    float* la = sA[wave];
    float* rb = sB[wave];
    float av[16], bv[16];
    float ca = 0.f, cb = 0.f;
#pragma unroll
    for (int i = 0; i < 16; ++i) {
      const int s = i*64 + lane;
      float x = la[s]; av[i] = x;
      float y = rb[s]; bv[i] = y;
#pragma unroll
      for (int off = 1; off <= 32; off <<= 1) {
        float ux = __shfl_up(x, off, 64);
        float uy = __shfl_up(y, off, 64);
        if (lane >= off) { x += ux; y += uy; }
      }
      la[s] = x + ca;                 // inclusive fwd cumsum of left_sm
      rb[s] = y + cb;                 // inclusive fwd cumsum of right_sm
      ca += __shfl(x, 63, 64);
      cb += __shfl(y, 63, 64);
    }
    const float TA = ca, TB = cb;
#pragma unroll
    for (int i = 0; i < 16; ++i) {
      const int s = i*64 + lane;
      const float fa = la[s], fb = rb[s];
      const float rl = TA - fa + av[i];   // rev cumsum of left
      const float rr = TB - fb + bv[i];   // rev cumsum of right
      la[s] = fa * rr + rl * fb;          // local_mask
    }
  }
  __syncthreads();

  // ---- local scores, softmax*mask, renormalize (into sB) ----
  scores(Qlo, Klo, sB);
  __syncthreads();
  {
    float* row = sB[wave];
    const float* mrow = sA[wave];
    float vals[16];
    float mx = -3.0e38f;
#pragma unroll
    for (int i = 0; i < 16; ++i) { vals[i] = row[i*64 + lane]; mx = fmaxf(mx, vals[i]); }
#pragma unroll
    for (int off = 32; off >= 1; off >>= 1) mx = fmaxf(mx, __shfl_xor(mx, off, 64));
    float msum = 0.f;
#pragma unroll
    for (int i = 0; i < 16; ++i) {
      vals[i] = expf(vals[i] - mx) * mrow[i*64 + lane];  // softmax denom cancels in renorm
      msum += vals[i];
    }
#pragma unroll
    for (int off = 32; off >= 1; off >>= 1) msum += __shfl_xor(msum, off, 64);
    const float minv = 1.f / msum;
#pragma unroll
    for (int i = 0; i < 16; ++i) row[i*64 + lane] = vals[i] * minv;
  }
  __syncthreads();

  // ---- global scores, softmax, combine (into sA) ----
  scores(Qg, Kg, sA);
  __syncthreads();
  {
    float* row = sA[wave];
    const float* lrow = sB[wave];
    float vals[16];
    float mx = -3.0e38f;
#pragma unroll
    for (int i = 0; i < 16; ++i) { vals[i] = row[i*64 + lane]; mx = fmaxf(mx, vals[i]); }
#pragma unroll
    for (int off = 32; off >= 1; off >>= 1) mx = fmaxf(mx, __shfl_xor(mx, off, 64));
    float sum = 0.f;
#pragma unroll
    for (int i = 0; i < 16; ++i) { vals[i] = expf(vals[i] - mx); sum += vals[i]; }
#pragma unroll
    for (int off = 32; off >= 1; off >>= 1) sum += __shfl_xor(sum, off, 64);
    const float inv = 1.f / sum;
#pragma unroll
    for (int i = 0; i < 16; ++i) {
      const int s = i*64 + lane;
      row[s] = 0.5f * (vals[i] * inv + lrow[s]);
    }
  }
  __syncthreads();

  // ---- PV: waves partition s, lane = d; cross-wave reduce via LDS (reuse sB) ----
  {
    float acc[8];
#pragma unroll
    for (int r = 0; r < 8; ++r) acc[r] = 0.f;
    const float* vp = Vg + (size_t)(wave * 128) * 64 + lane;
#pragma unroll 4
    for (int j = 0; j < 128; ++j) {
      const float vv = vp[(size_t)j * 64];
      const int s = wave * 128 + j;
#pragma unroll
      for (int r = 0; r < 8; ++r) acc[r] += sA[r][s] * vv;
    }
    float* sRed = &sB[0][0];
#pragma unroll
    for (int r = 0; r < 8; ++r) sRed[(wave*8 + r)*64 + lane] = acc[r];
  }
  __syncthreads();
  {
    const float* sRed = &sB[0][0];
    const int r = wave, d = lane;
    float acc = 0.f;
#pragma unroll
    for (int w = 0; w < 8; ++w) acc += sRed[(w*8 + r)*64 + d];
    const int b2 = bh >> 4, h = bh & 15;
    attnOut[((size_t)(t0 + r) * 4 + b2) * 1024 + h*64 + d] = acc;
  }
}

extern "C" void kernel_launch(void* const* d_in, const int* in_sizes, int n_in,
                              void* d_out, int out_size, void* d_ws, size_t ws_size,
                              hipStream_t stream) {
  const float* x     = (const float*)d_in[0];
  const float* w_in  = (const float*)d_in[1];
  const float* b_in  = (const float*)d_in[2];
  const float* w_out = (const float*)d_in[3];
  const float* b_out = (const float*)d_in[4];

  float* proj = (float*)d_ws;                          // [9][64][1024][64]
  float* attn = proj + (size_t)9 * 64 * 1024 * 64;     // [1024][4][1024]
  float* out  = (float*)d_out;

  // proj = x @ w_in^T + b_in, scatter to head layout with q/q_local scaling
  gemm_nt<1><<<dim3(32, 72), 256, 0, stream>>>(x, w_in, b_in, proj, 4096, 9216, 1024);
  // fused attention
  attn_fused<<<dim3(64, 128), 512, 0, stream>>>(proj, attn);
  // out = attn @ w_out^T + b_out
  gemm_nt<0><<<dim3(32, 8), 256, 0, stream>>>(attn, w_out, b_out, out, 4096, 1024, 1024);
}

// Round 2
// 2010.500 us; speedup vs baseline: 1.3108x; 1.3108x over previous
//
#include <hip/hip_runtime.h>
#include <math.h>

// ws layout (160 MiB total):
//   Ph: _Float16 [9][64][1024][64]  (72 MiB)  "hi" fp16 split of proj
//   Pl: _Float16 [9][64][1024][64]  (72 MiB)  "lo" fp16 split of proj
//   attn: float [1024][4][1024]     (16 MiB)
// w order: 0=q,1=k,2=v,3=q_left,4=k_left,5=q_right,6=k_right,7=q_local,8=k_local
// layout per matrix: [bh][t][d]  EXCEPT w==2 (v) stored transposed [bh][d][t]

typedef _Float16 half8 __attribute__((ext_vector_type(8)));
typedef float f32x4 __attribute__((ext_vector_type(4)));

#define MFMA16(A, B, C) __builtin_amdgcn_mfma_f32_16x16x32_f16(A, B, C, 0, 0, 0)

#define STR 1028
#define SMEM_BYTES (2 * 16 * STR * 4)

// ---------------- GEMM: C[m,n] = sum_k A[m,k]*B[n,k] + bias[n] ----------------
template<int MODE>
__global__ __launch_bounds__(256)
void gemm_nt(const float* __restrict__ A, const float* __restrict__ B,
             const float* __restrict__ bias, float* __restrict__ C,
             _Float16* __restrict__ Ph, _Float16* __restrict__ Pl,
             int M, int N, int K) {
  __shared__ float As[16][132];
  __shared__ float Bs[16][132];
  const int tid = threadIdx.x;
  const int m0 = blockIdx.x * 128;
  const int n0 = blockIdx.y * 128;
  const int tx = tid & 15;
  const int ty = tid >> 4;
  const int lrow = tid & 127;
  const int lk = (tid >> 7) * 8;

  float acc[8][8];
#pragma unroll
  for (int i = 0; i < 8; ++i)
#pragma unroll
    for (int j = 0; j < 8; ++j) acc[i][j] = 0.f;

  const float* ap = A + (size_t)(m0 + lrow) * K + lk;
  const float* bp = B + (size_t)(n0 + lrow) * K + lk;

  for (int k0 = 0; k0 < K; k0 += 16) {
    float4 av0 = *(const float4*)(ap + k0);
    float4 av1 = *(const float4*)(ap + k0 + 4);
    float4 bv0 = *(const float4*)(bp + k0);
    float4 bv1 = *(const float4*)(bp + k0 + 4);
    As[lk+0][lrow] = av0.x; As[lk+1][lrow] = av0.y;
    As[lk+2][lrow] = av0.z; As[lk+3][lrow] = av0.w;
    As[lk+4][lrow] = av1.x; As[lk+5][lrow] = av1.y;
    As[lk+6][lrow] = av1.z; As[lk+7][lrow] = av1.w;
    Bs[lk+0][lrow] = bv0.x; Bs[lk+1][lrow] = bv0.y;
    Bs[lk+2][lrow] = bv0.z; Bs[lk+3][lrow] = bv0.w;
    Bs[lk+4][lrow] = bv1.x; Bs[lk+5][lrow] = bv1.y;
    Bs[lk+6][lrow] = bv1.z; Bs[lk+7][lrow] = bv1.w;
    __syncthreads();
#pragma unroll
    for (int k = 0; k < 16; ++k) {
      float a[8], b[8];
      *(float4*)&a[0] = *(const float4*)&As[k][ty*4];
      *(float4*)&a[4] = *(const float4*)&As[k][64 + ty*4];
      *(float4*)&b[0] = *(const float4*)&Bs[k][tx*4];
      *(float4*)&b[4] = *(const float4*)&Bs[k][64 + tx*4];
#pragma unroll
      for (int i = 0; i < 8; ++i)
#pragma unroll
        for (int j = 0; j < 8; ++j) acc[i][j] += a[i] * b[j];
    }
    __syncthreads();
  }

#pragma unroll
  for (int i = 0; i < 8; ++i) {
    const int mi = m0 + ((i < 4) ? (ty*4 + i) : (64 + ty*4 + i - 4));
#pragma unroll
    for (int j = 0; j < 8; ++j) {
      const int nj = n0 + ((j < 4) ? (tx*4 + j) : (64 + tx*4 + j - 4));
      float v = acc[i][j] + bias[nj];
      if (MODE == 0) {
        C[(size_t)mi * N + nj] = v;
      } else {
        const int w = nj >> 10, hh = (nj >> 6) & 15, d = nj & 63;
        if (w == 0 || w == 7) v *= 0.125f;   // hd^-0.5
        const int t = mi >> 2, b2 = mi & 3;
        const size_t base = ((size_t)w * 64 + (b2 * 16 + hh)) * 65536;
        const size_t idx = (w == 2) ? base + (size_t)d * 1024 + t
                                    : base + (size_t)t * 64 + d;
        _Float16 h16 = (_Float16)v;
        _Float16 l16 = (_Float16)(v - (float)h16);
        Ph[idx] = h16;
        Pl[idx] = l16;
      }
    }
  }
}

// ---------------- fused attention via split-fp16 MFMA ----------------
// grid (64 bh, 64 row-blocks of R=16), block 512 (8 waves), dynamic LDS 128.5KB
__global__ __launch_bounds__(512)
void attn_mfma(const _Float16* __restrict__ Ph, const _Float16* __restrict__ Pl,
               float* __restrict__ attnOut) {
  extern __shared__ float smem[];
  float* sA = smem;              // [16][STR]
  float* sB = smem + 16 * STR;   // [16][STR]
  const int bh = blockIdx.x;
  const int t0 = blockIdx.y << 4;
  const int tid = threadIdx.x;
  const int wave = tid >> 6, lane = tid & 63;
  const int lr = lane & 15;            // fragment row/col
  const int lk8 = (lane >> 4) << 3;    // fragment k offset
  const int crow = (lane >> 4) << 2;   // C fragment row base

  auto mbase = [&](int w) { return ((size_t)w * 64 + bh) * 65536; };

  // S[r][s] = sum_d Q[t0+r][d]*K[s][d]; wave covers s in [wave*128, wave*128+128)
  auto scores = [&](int wq, int wk, float* S) {
    const _Float16* qh = Ph + mbase(wq) + (size_t)(t0 + lr) * 64 + lk8;
    const _Float16* ql = Pl + mbase(wq) + (size_t)(t0 + lr) * 64 + lk8;
    const half8 ah0 = *(const half8*)qh;
    const half8 ah1 = *(const half8*)(qh + 32);
    const half8 al0 = *(const half8*)ql;
    const half8 al1 = *(const half8*)(ql + 32);
    const _Float16* kbh = Ph + mbase(wk);
    const _Float16* kbl = Pl + mbase(wk);
    const int sbase = wave << 7;
#pragma unroll
    for (int tp = 0; tp < 4; ++tp) {
      const int s0 = sbase + tp * 32;
      const _Float16* kh0 = kbh + (size_t)(s0 + lr) * 64 + lk8;
      const _Float16* kl0 = kbl + (size_t)(s0 + lr) * 64 + lk8;
      const _Float16* kh1 = kh0 + 16 * 64;
      const _Float16* kl1 = kl0 + 16 * 64;
      half8 b0h0 = *(const half8*)kh0, b0h1 = *(const half8*)(kh0 + 32);
      half8 b0l0 = *(const half8*)kl0, b0l1 = *(const half8*)(kl0 + 32);
      half8 b1h0 = *(const half8*)kh1, b1h1 = *(const half8*)(kh1 + 32);
      half8 b1l0 = *(const half8*)kl1, b1l1 = *(const half8*)(kl1 + 32);
      f32x4 acc0 = {0.f, 0.f, 0.f, 0.f}, acc1 = {0.f, 0.f, 0.f, 0.f};
      acc0 = MFMA16(ah0, b0h0, acc0);  acc1 = MFMA16(ah0, b1h0, acc1);
      acc0 = MFMA16(ah1, b0h1, acc0);  acc1 = MFMA16(ah1, b1h1, acc1);
      acc0 = MFMA16(ah0, b0l0, acc0);  acc1 = MFMA16(ah0, b1l0, acc1);
      acc0 = MFMA16(ah1, b0l1, acc0);  acc1 = MFMA16(ah1, b1l1, acc1);
      acc0 = MFMA16(al0, b0h0, acc0);  acc1 = MFMA16(al0, b1h0, acc1);
      acc0 = MFMA16(al1, b0h1, acc0);  acc1 = MFMA16(al1, b1h1, acc1);
#pragma unroll
      for (int r = 0; r < 4; ++r) {
        S[(crow + r) * STR + s0 + lr] = acc0[r];
        S[(crow + r) * STR + s0 + 16 + lr] = acc1[r];
      }
    }
  };

  // normalize 2 rows (this wave's) of S in place
  auto softmax2 = [&](float* S) {
#pragma unroll
    for (int rr = 0; rr < 2; ++rr) {
      float* row = S + (2 * wave + rr) * STR;
      float vals[16];
      float mx = -3.0e38f;
#pragma unroll
      for (int i = 0; i < 16; ++i) { vals[i] = row[i*64 + lane]; mx = fmaxf(mx, vals[i]); }
#pragma unroll
      for (int off = 32; off >= 1; off >>= 1) mx = fmaxf(mx, __shfl_xor(mx, off, 64));
      float sum = 0.f;
#pragma unroll
      for (int i = 0; i < 16; ++i) { vals[i] = expf(vals[i] - mx); sum += vals[i]; }
#pragma unroll
      for (int off = 32; off >= 1; off >>= 1) sum += __shfl_xor(sum, off, 64);
      const float inv = 1.f / sum;
#pragma unroll
      for (int i = 0; i < 16; ++i) row[i*64 + lane] = vals[i] * inv;
    }
  };

  // ---- left/right scores ----
  scores(3, 4, sA);
  scores(5, 6, sB);
  __syncthreads();
  softmax2(sA);
  softmax2(sB);
  // no barrier: mask phase touches only this wave's rows

  // ---- cumsums -> local_mask into sA ----
  for (int rr = 0; rr < 2; ++rr) {
    float* la = sA + (2 * wave + rr) * STR;
    float* rb = sB + (2 * wave + rr) * STR;
    float av[16], af[16], bv[16], bf[16];
    float ca = 0.f, cb = 0.f;
#pragma unroll
    for (int i = 0; i < 16; ++i) {
      float x = la[i*64 + lane]; av[i] = x;
      float y = rb[i*64 + lane]; bv[i] = y;
#pragma unroll
      for (int off = 1; off <= 32; off <<= 1) {
        float ux = __shfl_up(x, off, 64);
        float uy = __shfl_up(y, off, 64);
        if (lane >= off) { x += ux; y += uy; }
      }
      af[i] = x + ca;
      bf[i] = y + cb;
      ca += __shfl(x, 63, 64);
      cb += __shfl(y, 63, 64);
    }
    const float TA = ca, TB = cb;
#pragma unroll
    for (int i = 0; i < 16; ++i) {
      const float rl = TA - af[i] + av[i];   // reverse cumsum (left)
      const float rr2 = TB - bf[i] + bv[i];  // reverse cumsum (right)
      la[i*64 + lane] = af[i] * rr2 + rl * bf[i];   // local_mask
    }
  }
  __syncthreads();

  // ---- local scores, exp*mask, renormalize -> sB ----
  scores(7, 8, sB);
  __syncthreads();
  for (int rr = 0; rr < 2; ++rr) {
    float* row = sB + (2 * wave + rr) * STR;
    const float* mrow = sA + (2 * wave + rr) * STR;
    float vals[16];
    float mx = -3.0e38f;
#pragma unroll
    for (int i = 0; i < 16; ++i) { vals[i] = row[i*64 + lane]; mx = fmaxf(mx, vals[i]); }
#pragma unroll
    for (int off = 32; off >= 1; off >>= 1) mx = fmaxf(mx, __shfl_xor(mx, off, 64));
    float msum = 0.f;
#pragma unroll
    for (int i = 0; i < 16; ++i) {
      vals[i] = expf(vals[i] - mx) * mrow[i*64 + lane];
      msum += vals[i];
    }
#pragma unroll
    for (int off = 32; off >= 1; off >>= 1) msum += __shfl_xor(msum, off, 64);
    const float minv = 1.f / msum;
#pragma unroll
    for (int i = 0; i < 16; ++i) row[i*64 + lane] = vals[i] * minv;
  }
  __syncthreads();

  // ---- global scores, softmax, combine -> sA ----
  scores(0, 1, sA);
  __syncthreads();
  for (int rr = 0; rr < 2; ++rr) {
    float* row = sA + (2 * wave + rr) * STR;
    const float* lrow = sB + (2 * wave + rr) * STR;
    float vals[16];
    float mx = -3.0e38f;
#pragma unroll
    for (int i = 0; i < 16; ++i) { vals[i] = row[i*64 + lane]; mx = fmaxf(mx, vals[i]); }
#pragma unroll
    for (int off = 32; off >= 1; off >>= 1) mx = fmaxf(mx, __shfl_xor(mx, off, 64));
    float sum = 0.f;
#pragma unroll
    for (int i = 0; i < 16; ++i) { vals[i] = expf(vals[i] - mx); sum += vals[i]; }
#pragma unroll
    for (int off = 32; off >= 1; off >>= 1) sum += __shfl_xor(sum, off, 64);
    const float inv = 1.f / sum;
#pragma unroll
    for (int i = 0; i < 16; ++i)
      row[i*64 + lane] = 0.5f * (vals[i] * inv + lrow[i*64 + lane]);
  }
  __syncthreads();

  // ---- PV via MFMA: A = P (split on the fly), B = V^T (pre-split) ----
  f32x4 cacc[4];
#pragma unroll
  for (int dt = 0; dt < 4; ++dt) cacc[dt] = (f32x4){0.f, 0.f, 0.f, 0.f};
  {
    const _Float16* vbh = Ph + mbase(2);
    const _Float16* vbl = Pl + mbase(2);
    const int sk0 = wave << 7;
#pragma unroll
    for (int kk = 0; kk < 4; ++kk) {
      const int sk = sk0 + kk * 32;
      const float* pp = sA + lr * STR + sk + lk8;
      float pv[8];
      *(float4*)&pv[0] = *(const float4*)pp;
      *(float4*)&pv[4] = *(const float4*)(pp + 4);
      half8 pah, pal;
#pragma unroll
      for (int j = 0; j < 8; ++j) {
        _Float16 h16 = (_Float16)pv[j];
        pah[j] = h16;
        pal[j] = (_Float16)(pv[j] - (float)h16);
      }
#pragma unroll
      for (int dt = 0; dt < 4; ++dt) {
        const _Float16* vh = vbh + (size_t)((dt << 4) + lr) * 1024 + sk + lk8;
        const _Float16* vl = vbl + (size_t)((dt << 4) + lr) * 1024 + sk + lk8;
        half8 bh8 = *(const half8*)vh;
        half8 bl8 = *(const half8*)vl;
        cacc[dt] = MFMA16(pah, bh8, cacc[dt]);
        cacc[dt] = MFMA16(pah, bl8, cacc[dt]);
        cacc[dt] = MFMA16(pal, bh8, cacc[dt]);
      }
    }
  }
  __syncthreads();   // all P reads done before smem reuse

  // partials: [8 waves][16 rows][64 d], row stride 65 to dodge bank conflicts
#pragma unroll
  for (int dt = 0; dt < 4; ++dt)
#pragma unroll
    for (int r = 0; r < 4; ++r)
      smem[(wave * 16 + crow + r) * 65 + dt * 16 + lr] = cacc[dt][r];
  __syncthreads();

  {
    const int b2 = bh >> 4, hh = bh & 15;
#pragma unroll
    for (int o = tid; o < 1024; o += 512) {
      const int r = o >> 6, d = o & 63;
      float acc = 0.f;
#pragma unroll
      for (int w = 0; w < 8; ++w) acc += smem[(w * 16 + r) * 65 + d];
      attnOut[((size_t)(t0 + r) * 4 + b2) * 1024 + hh * 64 + d] = acc;
    }
  }
}

extern "C" void kernel_launch(void* const* d_in, const int* in_sizes, int n_in,
                              void* d_out, int out_size, void* d_ws, size_t ws_size,
                              hipStream_t stream) {
  const float* x     = (const float*)d_in[0];
  const float* w_in  = (const float*)d_in[1];
  const float* b_in  = (const float*)d_in[2];
  const float* w_out = (const float*)d_in[3];
  const float* b_out = (const float*)d_in[4];

  const size_t NP = (size_t)9 * 64 * 1024 * 64;
  _Float16* Ph = (_Float16*)d_ws;
  _Float16* Pl = Ph + NP;
  float* attn = (float*)(Pl + NP);
  float* out  = (float*)d_out;

  static int smem_set = 0;
  (void)hipFuncSetAttribute((const void*)attn_mfma,
                            hipFuncAttributeMaxDynamicSharedMemorySize,
                            SMEM_BYTES);

  // proj = x @ w_in^T + b_in -> fp16 split (h,l), head-major; v transposed
  gemm_nt<1><<<dim3(32, 72), 256, 0, stream>>>(x, w_in, b_in, nullptr, Ph, Pl, 4096, 9216, 1024);
  // fused attention
  attn_mfma<<<dim3(64, 64), 512, SMEM_BYTES, stream>>>(Ph, Pl, attn);
  // out = attn @ w_out^T + b_out
  gemm_nt<0><<<dim3(32, 8), 256, 0, stream>>>(attn, w_out, b_out, out, nullptr, nullptr, 4096, 1024, 1024);
}

// Round 3
// 1767.557 us; speedup vs baseline: 1.4910x; 1.1374x over previous
//
#include <hip/hip_runtime.h>
#include <math.h>

// ws layout (exactly 160 MiB):
//   Ph: _Float16 [9][64][1024][64]  (72 MiB)  "hi" fp16 split of proj
//   Pl: _Float16 [9][64][1024][64]  (72 MiB)  "lo" fp16 split of proj
//   attn: float [1024][4][1024]     (16 MiB)
// w order: 0=q,1=k,2=v,3=q_left,4=k_left,5=q_right,6=k_right,7=q_local,8=k_local
// layout per matrix: [bh][t][d]  EXCEPT w==2 (v) stored transposed [bh][d][t]

typedef _Float16 half8 __attribute__((ext_vector_type(8)));
typedef _Float16 half4v __attribute__((ext_vector_type(4)));
typedef float f32x4 __attribute__((ext_vector_type(4)));

#define MFMA16(A, B, C) __builtin_amdgcn_mfma_f32_16x16x32_f16(A, B, C, 0, 0, 0)

#define STRP 1028
#define SMEM_ATTN ((16 * STRP + 6 * 128) * 4)

// ---------------- split-fp16 MFMA GEMM: C = A * B^T + bias ----------------
// A: M x K fp32 row-major; B: N x K fp32 row-major. M,N mult of 128, K mult of 64.
// MODE 0: C[mi*N+nj] fp32.  MODE 1: proj scatter to Ph/Pl head layout.
template<int MODE>
__global__ __launch_bounds__(256, 2)
void gemm_mfma(const float* __restrict__ A, const float* __restrict__ B,
               const float* __restrict__ bias, float* __restrict__ C,
               _Float16* __restrict__ Ph, _Float16* __restrict__ Pl,
               int M, int N, int K) {
  __shared__ _Float16 Ah[128 * 64], Al[128 * 64], Bh[128 * 64], Bl[128 * 64];
  const int tid = threadIdx.x;
  const int m0 = blockIdx.x * 128, n0 = blockIdx.y * 128;
  const int wave = tid >> 6, lane = tid & 63;
  const int g2 = lane >> 4, c = lane & 15;
  const int wm = (wave >> 1) * 64, wn = (wave & 1) * 64;

  const int srow = tid >> 1;           // 0..127
  const int shalf = (tid & 1) * 32;    // 0 or 32
  const int swz = (srow & 7) << 3;     // XOR swizzle (units of halves)
  const float* ap = A + (size_t)(m0 + srow) * K + shalf;
  const float* bp = B + (size_t)(n0 + srow) * K + shalf;

  f32x4 acc[4][4];
#pragma unroll
  for (int i = 0; i < 4; ++i)
#pragma unroll
    for (int j = 0; j < 4; ++j) acc[i][j] = (f32x4){0.f, 0.f, 0.f, 0.f};

  for (int k0 = 0; k0 < K; k0 += 64) {
    float4 av[8], bv[8];
#pragma unroll
    for (int u = 0; u < 8; ++u) {
      av[u] = *(const float4*)(ap + k0 + u * 4);
      bv[u] = *(const float4*)(bp + k0 + u * 4);
    }
    __syncthreads();   // previous compute done before overwrite
#pragma unroll
    for (int u = 0; u < 8; ++u) {
      const int cc = (shalf + u * 4) ^ swz;
      half4v h4a, l4a, h4b, l4b;
      const float* fa = (const float*)&av[u];
      const float* fb = (const float*)&bv[u];
#pragma unroll
      for (int e = 0; e < 4; ++e) {
        _Float16 ha = (_Float16)fa[e];
        h4a[e] = ha; l4a[e] = (_Float16)(fa[e] - (float)ha);
        _Float16 hb = (_Float16)fb[e];
        h4b[e] = hb; l4b[e] = (_Float16)(fb[e] - (float)hb);
      }
      *(half4v*)&Ah[srow * 64 + cc] = h4a;
      *(half4v*)&Al[srow * 64 + cc] = l4a;
      *(half4v*)&Bh[srow * 64 + cc] = h4b;
      *(half4v*)&Bl[srow * 64 + cc] = l4b;
    }
    __syncthreads();
#pragma unroll
    for (int ks = 0; ks < 2; ++ks) {
      const int kb = ks * 32 + 8 * g2;
      half8 a_h[4], a_l[4];
#pragma unroll
      for (int i = 0; i < 4; ++i) {
        const int row = wm + i * 16 + c;
        const int cc = kb ^ ((row & 7) << 3);
        a_h[i] = *(const half8*)&Ah[row * 64 + cc];
        a_l[i] = *(const half8*)&Al[row * 64 + cc];
      }
#pragma unroll
      for (int j = 0; j < 4; ++j) {
        const int rowb = wn + j * 16 + c;
        const int cc = kb ^ ((rowb & 7) << 3);
        const half8 b_h = *(const half8*)&Bh[rowb * 64 + cc];
        const half8 b_l = *(const half8*)&Bl[rowb * 64 + cc];
#pragma unroll
        for (int i = 0; i < 4; ++i) {
          acc[i][j] = MFMA16(a_h[i], b_h, acc[i][j]);
          acc[i][j] = MFMA16(a_h[i], b_l, acc[i][j]);
          acc[i][j] = MFMA16(a_l[i], b_h, acc[i][j]);
        }
      }
    }
  }

  // epilogue: C layout col=lane&15, row=(lane>>4)*4+reg
#pragma unroll
  for (int j = 0; j < 4; ++j) {
    const int nj = n0 + wn + j * 16 + c;
    const float bz = bias[nj];
    if (MODE == 0) {
#pragma unroll
      for (int i = 0; i < 4; ++i)
#pragma unroll
        for (int q = 0; q < 4; ++q) {
          const int mi = m0 + wm + i * 16 + 4 * g2 + q;
          C[(size_t)mi * N + nj] = acc[i][j][q] + bz;
        }
    } else {
      const int w = nj >> 10, hh = (nj >> 6) & 15, d = nj & 63;
      const float scale = (w == 0 || w == 7) ? 0.125f : 1.0f;
#pragma unroll
      for (int i = 0; i < 4; ++i)
#pragma unroll
        for (int q = 0; q < 4; ++q) {
          const int mi = m0 + wm + i * 16 + 4 * g2 + q;
          const int t = mi >> 2, b2 = mi & 3;
          const size_t bb = ((size_t)w * 64 + (b2 * 16 + hh)) * 65536;
          const size_t idx = (w == 2) ? bb + (size_t)d * 1024 + t
                                      : bb + (size_t)t * 64 + d;
          const float v = (acc[i][j][q] + bz) * scale;
          const _Float16 h16 = (_Float16)v;
          Ph[idx] = h16;
          Pl[idx] = (_Float16)(v - (float)h16);
        }
    }
  }
}

// ---------------- fused attention: scores in registers ----------------
// grid (64 tblocks, 64 bh), block 512 (8 waves), dynamic LDS 68864 B -> 2 WG/CU
__global__ __launch_bounds__(512, 4)
void attn_mfma(const _Float16* __restrict__ Ph, const _Float16* __restrict__ Pl,
               float* __restrict__ attnOut) {
  extern __shared__ float smem[];
  float* sP = smem;                  // [16][STRP] fp32
  float* sRed = smem + 16 * STRP;    // [6][16][8] scratch
  const int t0 = blockIdx.x << 4;
  const int bh = blockIdx.y;
  const int tid = threadIdx.x;
  const int wave = tid >> 6, lane = tid & 63;
  const int g2 = lane >> 4, c = lane & 15;
  const int sbase = wave << 7;       // this wave's s-slice base (128 cols)
  // reg layout: v[m][q] = S[4*g2+q][sbase + 16*m + c]

  auto mbase = [&](int w) { return ((size_t)w * 64 + bh) * 65536; };

  auto scores = [&](int wq, int wk, f32x4* out) {
    const _Float16* qh = Ph + mbase(wq) + (size_t)(t0 + c) * 64 + 8 * g2;
    const _Float16* ql = Pl + mbase(wq) + (size_t)(t0 + c) * 64 + 8 * g2;
    const half8 ah0 = *(const half8*)qh, ah1 = *(const half8*)(qh + 32);
    const half8 al0 = *(const half8*)ql, al1 = *(const half8*)(ql + 32);
    const _Float16* kbh = Ph + mbase(wk);
    const _Float16* kbl = Pl + mbase(wk);
#pragma unroll
    for (int tp = 0; tp < 4; ++tp) {
      const int s0 = sbase + tp * 32;
      const _Float16* kh0 = kbh + (size_t)(s0 + c) * 64 + 8 * g2;
      const _Float16* kl0 = kbl + (size_t)(s0 + c) * 64 + 8 * g2;
      const half8 b0h0 = *(const half8*)kh0, b0h1 = *(const half8*)(kh0 + 32);
      const half8 b0l0 = *(const half8*)kl0, b0l1 = *(const half8*)(kl0 + 32);
      const half8 b1h0 = *(const half8*)(kh0 + 1024), b1h1 = *(const half8*)(kh0 + 1056);
      const half8 b1l0 = *(const half8*)(kl0 + 1024), b1l1 = *(const half8*)(kl0 + 1056);
      f32x4 a0 = {0.f, 0.f, 0.f, 0.f}, a1 = {0.f, 0.f, 0.f, 0.f};
      a0 = MFMA16(ah0, b0h0, a0);  a1 = MFMA16(ah0, b1h0, a1);
      a0 = MFMA16(ah1, b0h1, a0);  a1 = MFMA16(ah1, b1h1, a1);
      a0 = MFMA16(ah0, b0l0, a0);  a1 = MFMA16(ah0, b1l0, a1);
      a0 = MFMA16(ah1, b0l1, a0);  a1 = MFMA16(ah1, b1l1, a1);
      a0 = MFMA16(al0, b0h0, a0);  a1 = MFMA16(al0, b1h0, a1);
      a0 = MFMA16(al1, b0h1, a0);  a1 = MFMA16(al1, b1h1, a1);
      out[2 * tp] = a0;
      out[2 * tp + 1] = a1;
    }
  };

  auto grp_max = [&](const f32x4* v) {
    f32x4 m = v[0];
#pragma unroll
    for (int i = 1; i < 8; ++i)
#pragma unroll
      for (int q = 0; q < 4; ++q) m[q] = fmaxf(m[q], v[i][q]);
#pragma unroll
    for (int off = 1; off < 16; off <<= 1)
#pragma unroll
      for (int q = 0; q < 4; ++q) m[q] = fmaxf(m[q], __shfl_xor(m[q], off, 64));
    return m;
  };
  auto grp_sum = [&](f32x4 s) {
#pragma unroll
    for (int off = 1; off < 16; off <<= 1)
#pragma unroll
      for (int q = 0; q < 4; ++q) s[q] += __shfl_xor(s[q], off, 64);
    return s;
  };
  auto put = [&](int slot, f32x4 val) {
    if (c < 4) {
      const float x = (c == 0) ? val[0] : (c == 1) ? val[1] : (c == 2) ? val[2] : val[3];
      sRed[slot * 128 + (4 * g2 + c) * 8 + wave] = x;
    }
  };
  auto get_max = [&](int slot) {
    f32x4 r;
#pragma unroll
    for (int q = 0; q < 4; ++q) {
      const float* p = sRed + slot * 128 + (4 * g2 + q) * 8;
      r[q] = fmaxf(fmaxf(fmaxf(p[0], p[1]), fmaxf(p[2], p[3])),
                   fmaxf(fmaxf(p[4], p[5]), fmaxf(p[6], p[7])));
    }
    return r;
  };
  auto get_sum = [&](int slot) {
    f32x4 r;
#pragma unroll
    for (int q = 0; q < 4; ++q) {
      const float* p = sRed + slot * 128 + (4 * g2 + q) * 8;
      r[q] = ((p[0] + p[1]) + (p[2] + p[3])) + ((p[4] + p[5]) + (p[6] + p[7]));
    }
    return r;
  };
  auto get_pref = [&](int slot) {
    f32x4 r = {0.f, 0.f, 0.f, 0.f};
#pragma unroll
    for (int q = 0; q < 4; ++q) {
      const float* p = sRed + slot * 128 + (4 * g2 + q) * 8;
      float s = 0.f;
      for (int w = 0; w < wave; ++w) s += p[w];
      r[q] = s;
    }
    return r;
  };
  // inclusive prefix scan along s (4 rows at once); writes wave totals to slot
  auto scan = [&](f32x4* v, int slot) {
    f32x4 carry = {0.f, 0.f, 0.f, 0.f};
#pragma unroll
    for (int m = 0; m < 8; ++m) {
      f32x4 x = v[m];
#pragma unroll
      for (int off = 1; off < 16; off <<= 1)
#pragma unroll
        for (int q = 0; q < 4; ++q) {
          const float u = __shfl_up(x[q], off, 64);
          if (c >= off) x[q] += u;
        }
      x += carry;
#pragma unroll
      for (int q = 0; q < 4; ++q) carry[q] = __shfl(x[q], (lane & 48) | 15, 64);
      v[m] = x;
    }
    put(slot, carry);
  };

  f32x4 rv[8], lv[8];
  // ================= phase A: left/right -> local_mask (into lv) ============
  scores(5, 6, rv);                 // right
  scores(3, 4, lv);                 // left
  put(0, grp_max(rv));
  put(1, grp_max(lv));
  __syncthreads();                  // B1
  {
    const f32x4 MR = get_max(0), ML = get_max(1);
    f32x4 sR = {0.f, 0.f, 0.f, 0.f}, sL = {0.f, 0.f, 0.f, 0.f};
#pragma unroll
    for (int m = 0; m < 8; ++m) {
#pragma unroll
      for (int q = 0; q < 4; ++q) {
        rv[m][q] = expf(rv[m][q] - MR[q]);
        lv[m][q] = expf(lv[m][q] - ML[q]);
      }
      sR += rv[m];
      sL += lv[m];
    }
    put(2, grp_sum(sR));
    put(3, grp_sum(sL));
    __syncthreads();                // B2
    const f32x4 SR = get_sum(2), SL = get_sum(3);
    f32x4 iR, iL;
#pragma unroll
    for (int q = 0; q < 4; ++q) { iR[q] = 1.f / SR[q]; iL[q] = 1.f / SL[q]; }
#pragma unroll
    for (int m = 0; m < 8; ++m) { rv[m] *= iR; lv[m] *= iL; }
    scan(rv, 4);
    scan(lv, 5);
    __syncthreads();                // B3
    const f32x4 pR = get_pref(4), pL = get_pref(5);
#pragma unroll
    for (int m = 0; m < 8; ++m) { rv[m] += pR; lv[m] += pL; }
    // mask = af*(1-bfx) + (1-afx)*bf   (normalized totals == 1)
#pragma unroll
    for (int m = 7; m >= 0; --m) {
      f32x4 afx, bfx;
#pragma unroll
      for (int q = 0; q < 4; ++q) {
        const float ua = __shfl_up(lv[m][q], 1, 64);
        const float ub = __shfl_up(rv[m][q], 1, 64);
        const float la = (m > 0) ? __shfl(lv[m - 1][q], (lane & 48) | 15, 64) : pL[q];
        const float lb = (m > 0) ? __shfl(rv[m - 1][q], (lane & 48) | 15, 64) : pR[q];
        afx[q] = (c == 0) ? la : ua;
        bfx[q] = (c == 0) ? lb : ub;
      }
      lv[m] = lv[m] * (1.f - bfx) + (1.f - afx) * rv[m];
    }
  }
  // ================= phase B: global -> sP, local*mask += sP ================
  {
    f32x4 gv[8];
    scores(0, 1, gv);               // global
    put(0, grp_max(gv));
    __syncthreads();                // B4
    const f32x4 MG = get_max(0);
    f32x4 sG = {0.f, 0.f, 0.f, 0.f};
#pragma unroll
    for (int m = 0; m < 8; ++m) {
#pragma unroll
      for (int q = 0; q < 4; ++q) gv[m][q] = expf(gv[m][q] - MG[q]);
      sG += gv[m];
    }
    put(2, grp_sum(sG));
    __syncthreads();                // B5
    const f32x4 SG = get_sum(2);
    f32x4 iG;
#pragma unroll
    for (int q = 0; q < 4; ++q) iG[q] = 0.5f / SG[q];
#pragma unroll
    for (int m = 0; m < 8; ++m)
#pragma unroll
      for (int q = 0; q < 4; ++q)
        sP[(4 * g2 + q) * STRP + sbase + 16 * m + c] = gv[m][q] * iG[q];
  }
  {
    f32x4 ov[8];
    scores(7, 8, ov);               // local
    put(1, grp_max(ov));
    __syncthreads();                // B6
    const f32x4 MO = get_max(1);
    f32x4 sO = {0.f, 0.f, 0.f, 0.f};
#pragma unroll
    for (int m = 0; m < 8; ++m) {
#pragma unroll
      for (int q = 0; q < 4; ++q) ov[m][q] = expf(ov[m][q] - MO[q]) * lv[m][q];
      sO += ov[m];
    }
    put(3, grp_sum(sO));
    __syncthreads();                // B7
    const f32x4 SO = get_sum(3);
    f32x4 iO;
#pragma unroll
    for (int q = 0; q < 4; ++q) iO[q] = 0.5f / SO[q];
#pragma unroll
    for (int m = 0; m < 8; ++m)
#pragma unroll
      for (int q = 0; q < 4; ++q)
        sP[(4 * g2 + q) * STRP + sbase + 16 * m + c] += ov[m][q] * iO[q];
  }
  __syncthreads();                  // B8: P complete

  // ================= PV via MFMA =================
  f32x4 cacc[4];
#pragma unroll
  for (int dt = 0; dt < 4; ++dt) cacc[dt] = (f32x4){0.f, 0.f, 0.f, 0.f};
  {
    const _Float16* vbh = Ph + mbase(2);
    const _Float16* vbl = Pl + mbase(2);
#pragma unroll
    for (int kk = 0; kk < 4; ++kk) {
      const int sk = sbase + kk * 32;
      const float* pp = sP + c * STRP + sk + 8 * g2;
      float pv[8];
      *(float4*)&pv[0] = *(const float4*)pp;
      *(float4*)&pv[4] = *(const float4*)(pp + 4);
      half8 pah, pal;
#pragma unroll
      for (int j = 0; j < 8; ++j) {
        const _Float16 h16 = (_Float16)pv[j];
        pah[j] = h16;
        pal[j] = (_Float16)(pv[j] - (float)h16);
      }
#pragma unroll
      for (int dt = 0; dt < 4; ++dt) {
        const _Float16* vh = vbh + (size_t)(dt * 16 + c) * 1024 + sk + 8 * g2;
        const _Float16* vl = vbl + (size_t)(dt * 16 + c) * 1024 + sk + 8 * g2;
        const half8 bh8 = *(const half8*)vh;
        const half8 bl8 = *(const half8*)vl;
        cacc[dt] = MFMA16(pah, bh8, cacc[dt]);
        cacc[dt] = MFMA16(pah, bl8, cacc[dt]);
        cacc[dt] = MFMA16(pal, bh8, cacc[dt]);
      }
    }
  }
  __syncthreads();                  // all P reads done before reuse
#pragma unroll
  for (int dt = 0; dt < 4; ++dt)
#pragma unroll
    for (int q = 0; q < 4; ++q)
      sP[(wave * 16 + 4 * g2 + q) * 65 + dt * 16 + c] = cacc[dt][q];
  __syncthreads();
  {
    const int b2 = bh >> 4, hh = bh & 15;
    for (int o = tid; o < 1024; o += 512) {
      const int r = o >> 6, d = o & 63;
      float a = 0.f;
#pragma unroll
      for (int w = 0; w < 8; ++w) a += sP[(w * 16 + r) * 65 + d];
      attnOut[((size_t)(t0 + r) * 4 + b2) * 1024 + hh * 64 + d] = a;
    }
  }
}

extern "C" void kernel_launch(void* const* d_in, const int* in_sizes, int n_in,
                              void* d_out, int out_size, void* d_ws, size_t ws_size,
                              hipStream_t stream) {
  const float* x     = (const float*)d_in[0];
  const float* w_in  = (const float*)d_in[1];
  const float* b_in  = (const float*)d_in[2];
  const float* w_out = (const float*)d_in[3];
  const float* b_out = (const float*)d_in[4];

  const size_t NP = (size_t)9 * 64 * 1024 * 64;
  _Float16* Ph = (_Float16*)d_ws;
  _Float16* Pl = Ph + NP;
  float* attn = (float*)(Pl + NP);

  (void)hipFuncSetAttribute((const void*)attn_mfma,
                            hipFuncAttributeMaxDynamicSharedMemorySize,
                            SMEM_ATTN);

  // proj = x @ w_in^T + b_in -> fp16 h/l split, head-major; v transposed
  gemm_mfma<1><<<dim3(32, 72), 256, 0, stream>>>(x, w_in, b_in, nullptr, Ph, Pl, 4096, 9216, 1024);
  // fused attention
  attn_mfma<<<dim3(64, 64), 512, SMEM_ATTN, stream>>>(Ph, Pl, attn);
  // out = attn @ w_out^T + b_out
  gemm_mfma<0><<<dim3(32, 8), 256, 0, stream>>>(attn, w_out, b_out, (float*)d_out, nullptr, nullptr, 4096, 1024, 1024);
}

// Round 4
// 1224.237 us; speedup vs baseline: 2.1527x; 1.4438x over previous
//
#include <hip/hip_runtime.h>
#include <math.h>

// ws layout (exactly 160 MiB):
//   Ph: _Float16 [9][64][1024][64]  (72 MiB)  "hi" fp16 split of proj
//   Pl: _Float16 [9][64][1024][64]  (72 MiB)  "lo" fp16 split of proj
//   attn: float [1024][4][1024]     (16 MiB)
// w order: 0=q,1=k,2=v,3=q_left,4=k_left,5=q_right,6=k_right,7=q_local,8=k_local
// layout per matrix: [bh][t][d]  EXCEPT w==2 (v) stored transposed [bh][d][t]

typedef _Float16 half8 __attribute__((ext_vector_type(8)));
typedef _Float16 half4v __attribute__((ext_vector_type(4)));
typedef float f32x4 __attribute__((ext_vector_type(4)));

#define MFMA16(A, B, C) __builtin_amdgcn_mfma_f32_16x16x32_f16(A, B, C, 0, 0, 0)

#define STRP 1025
#define SMEM_ATTN ((16 * STRP + 6 * 128) * 4)

// ---------------- split-fp16 MFMA GEMM: C = A * B^T + bias ----------------
template<int MODE>
__global__ __launch_bounds__(256, 2)
void gemm_mfma(const float* __restrict__ A, const float* __restrict__ B,
               const float* __restrict__ bias, float* __restrict__ C,
               _Float16* __restrict__ Ph, _Float16* __restrict__ Pl,
               int M, int N, int K) {
  __shared__ _Float16 Ah[128 * 64], Al[128 * 64], Bh[128 * 64], Bl[128 * 64];
  const int tid = threadIdx.x;
  const int m0 = blockIdx.x * 128, n0 = blockIdx.y * 128;
  const int wave = tid >> 6, lane = tid & 63;
  const int g2 = lane >> 4, c = lane & 15;
  const int wm = (wave >> 1) * 64, wn = (wave & 1) * 64;

  const int srow = tid >> 1;
  const int shalf = (tid & 1) * 32;
  const int swz = (srow & 7) << 3;
  const float* ap = A + (size_t)(m0 + srow) * K + shalf;
  const float* bp = B + (size_t)(n0 + srow) * K + shalf;

  f32x4 acc[4][4];
#pragma unroll
  for (int i = 0; i < 4; ++i)
#pragma unroll
    for (int j = 0; j < 4; ++j) acc[i][j] = (f32x4){0.f, 0.f, 0.f, 0.f};

  for (int k0 = 0; k0 < K; k0 += 64) {
    float4 av[8], bv[8];
#pragma unroll
    for (int u = 0; u < 8; ++u) {
      av[u] = *(const float4*)(ap + k0 + u * 4);
      bv[u] = *(const float4*)(bp + k0 + u * 4);
    }
    __syncthreads();
#pragma unroll
    for (int u = 0; u < 8; ++u) {
      const int cc = (shalf + u * 4) ^ swz;
      half4v h4a, l4a, h4b, l4b;
      const float* fa = (const float*)&av[u];
      const float* fb = (const float*)&bv[u];
#pragma unroll
      for (int e = 0; e < 4; ++e) {
        _Float16 ha = (_Float16)fa[e];
        h4a[e] = ha; l4a[e] = (_Float16)(fa[e] - (float)ha);
        _Float16 hb = (_Float16)fb[e];
        h4b[e] = hb; l4b[e] = (_Float16)(fb[e] - (float)hb);
      }
      *(half4v*)&Ah[srow * 64 + cc] = h4a;
      *(half4v*)&Al[srow * 64 + cc] = l4a;
      *(half4v*)&Bh[srow * 64 + cc] = h4b;
      *(half4v*)&Bl[srow * 64 + cc] = l4b;
    }
    __syncthreads();
#pragma unroll
    for (int ks = 0; ks < 2; ++ks) {
      const int kb = ks * 32 + 8 * g2;
      half8 a_h[4], a_l[4];
#pragma unroll
      for (int i = 0; i < 4; ++i) {
        const int row = wm + i * 16 + c;
        const int cc = kb ^ ((row & 7) << 3);
        a_h[i] = *(const half8*)&Ah[row * 64 + cc];
        a_l[i] = *(const half8*)&Al[row * 64 + cc];
      }
#pragma unroll
      for (int j = 0; j < 4; ++j) {
        const int rowb = wn + j * 16 + c;
        const int cc = kb ^ ((rowb & 7) << 3);
        const half8 b_h = *(const half8*)&Bh[rowb * 64 + cc];
        const half8 b_l = *(const half8*)&Bl[rowb * 64 + cc];
#pragma unroll
        for (int i = 0; i < 4; ++i) {
          acc[i][j] = MFMA16(a_h[i], b_h, acc[i][j]);
          acc[i][j] = MFMA16(a_h[i], b_l, acc[i][j]);
          acc[i][j] = MFMA16(a_l[i], b_h, acc[i][j]);
        }
      }
    }
  }

#pragma unroll
  for (int j = 0; j < 4; ++j) {
    const int nj = n0 + wn + j * 16 + c;
    const float bz = bias[nj];
    if (MODE == 0) {
#pragma unroll
      for (int i = 0; i < 4; ++i)
#pragma unroll
        for (int q = 0; q < 4; ++q) {
          const int mi = m0 + wm + i * 16 + 4 * g2 + q;
          C[(size_t)mi * N + nj] = acc[i][j][q] + bz;
        }
    } else {
      const int w = nj >> 10, hh = (nj >> 6) & 15, d = nj & 63;
      const float scale = (w == 0 || w == 7) ? 0.125f : 1.0f;
#pragma unroll
      for (int i = 0; i < 4; ++i)
#pragma unroll
        for (int q = 0; q < 4; ++q) {
          const int mi = m0 + wm + i * 16 + 4 * g2 + q;
          const int t = mi >> 2, b2 = mi & 3;
          const size_t bb = ((size_t)w * 64 + (b2 * 16 + hh)) * 65536;
          const size_t idx = (w == 2) ? bb + (size_t)d * 1024 + t
                                      : bb + (size_t)t * 64 + d;
          const float v = (acc[i][j][q] + bz) * scale;
          const _Float16 h16 = (_Float16)v;
          Ph[idx] = h16;
          Pl[idx] = (_Float16)(v - (float)h16);
        }
    }
  }
}

// ---------------- fused attention: scores in registers, mask via LDS ----------------
// grid (64 tblocks, 64 bh), block 512 (8 waves), dynamic LDS 68672 B -> 2 WG/CU
__global__ __launch_bounds__(512, 4)
void attn_mfma(const _Float16* __restrict__ Ph, const _Float16* __restrict__ Pl,
               float* __restrict__ attnOut) {
  extern __shared__ float smem[];
  float* sP = smem;                  // [16][STRP] fp32: mask, then final P
  float* sRed = smem + 16 * STRP;    // [6][16][8] scratch
  const int t0 = blockIdx.x << 4;
  const int bh = blockIdx.y;
  const int tid = threadIdx.x;
  const int wave = tid >> 6, lane = tid & 63;
  const int g2 = lane >> 4, c = lane & 15;
  const int sbase = wave << 7;
  // reg layout: v[m][q] = S[4*g2+q][sbase + 16*m + c]

  auto mbase = [&](int w) { return ((size_t)w * 64 + bh) * 65536; };

  // 8 tiles of 16 cols; only one tile's B-fragments live at a time (16 regs)
  auto scores = [&](int wq, int wk, f32x4* out) {
    const _Float16* qh = Ph + mbase(wq) + (size_t)(t0 + c) * 64 + 8 * g2;
    const _Float16* ql = Pl + mbase(wq) + (size_t)(t0 + c) * 64 + 8 * g2;
    const half8 ah0 = *(const half8*)qh, ah1 = *(const half8*)(qh + 32);
    const half8 al0 = *(const half8*)ql, al1 = *(const half8*)(ql + 32);
    const _Float16* kbh = Ph + mbase(wk);
    const _Float16* kbl = Pl + mbase(wk);
#pragma unroll
    for (int tp = 0; tp < 8; ++tp) {
      const int s0 = sbase + tp * 16;
      const _Float16* kh = kbh + (size_t)(s0 + c) * 64 + 8 * g2;
      const _Float16* kl = kbl + (size_t)(s0 + c) * 64 + 8 * g2;
      const half8 bh0 = *(const half8*)kh, bh1 = *(const half8*)(kh + 32);
      const half8 bl0 = *(const half8*)kl, bl1 = *(const half8*)(kl + 32);
      f32x4 a = {0.f, 0.f, 0.f, 0.f};
      a = MFMA16(ah0, bh0, a);
      a = MFMA16(ah1, bh1, a);
      a = MFMA16(ah0, bl0, a);
      a = MFMA16(ah1, bl1, a);
      a = MFMA16(al0, bh0, a);
      a = MFMA16(al1, bh1, a);
      out[tp] = a;
    }
  };

  auto grp_max = [&](const f32x4* v) {
    f32x4 m = v[0];
#pragma unroll
    for (int i = 1; i < 8; ++i)
#pragma unroll
      for (int q = 0; q < 4; ++q) m[q] = fmaxf(m[q], v[i][q]);
#pragma unroll
    for (int off = 1; off < 16; off <<= 1)
#pragma unroll
      for (int q = 0; q < 4; ++q) m[q] = fmaxf(m[q], __shfl_xor(m[q], off, 64));
    return m;
  };
  auto grp_sum = [&](f32x4 s) {
#pragma unroll
    for (int off = 1; off < 16; off <<= 1)
#pragma unroll
      for (int q = 0; q < 4; ++q) s[q] += __shfl_xor(s[q], off, 64);
    return s;
  };
  auto put = [&](int slot, f32x4 val) {
    if (c < 4) {
      const float x = (c == 0) ? val[0] : (c == 1) ? val[1] : (c == 2) ? val[2] : val[3];
      sRed[slot * 128 + (4 * g2 + c) * 8 + wave] = x;
    }
  };
  auto get_max = [&](int slot) {
    f32x4 r;
#pragma unroll
    for (int q = 0; q < 4; ++q) {
      const float* p = sRed + slot * 128 + (4 * g2 + q) * 8;
      r[q] = fmaxf(fmaxf(fmaxf(p[0], p[1]), fmaxf(p[2], p[3])),
                   fmaxf(fmaxf(p[4], p[5]), fmaxf(p[6], p[7])));
    }
    return r;
  };
  auto get_sum = [&](int slot) {
    f32x4 r;
#pragma unroll
    for (int q = 0; q < 4; ++q) {
      const float* p = sRed + slot * 128 + (4 * g2 + q) * 8;
      r[q] = ((p[0] + p[1]) + (p[2] + p[3])) + ((p[4] + p[5]) + (p[6] + p[7]));
    }
    return r;
  };
  auto get_pref = [&](int slot) {
    f32x4 r = {0.f, 0.f, 0.f, 0.f};
#pragma unroll
    for (int q = 0; q < 4; ++q) {
      const float* p = sRed + slot * 128 + (4 * g2 + q) * 8;
      float s = 0.f;
      for (int w = 0; w < wave; ++w) s += p[w];
      r[q] = s;
    }
    return r;
  };
  auto scan = [&](f32x4* v, int slot) {
    f32x4 carry = {0.f, 0.f, 0.f, 0.f};
#pragma unroll
    for (int m = 0; m < 8; ++m) {
      f32x4 x = v[m];
#pragma unroll
      for (int off = 1; off < 16; off <<= 1)
#pragma unroll
        for (int q = 0; q < 4; ++q) {
          const float u = __shfl_up(x[q], off, 64);
          if (c >= off) x[q] += u;
        }
      x += carry;
#pragma unroll
      for (int q = 0; q < 4; ++q) carry[q] = __shfl(x[q], (lane & 48) | 15, 64);
      v[m] = x;
    }
    put(slot, carry);
  };

  // ================= phase A: left/right -> local_mask -> sP ============
  {
    f32x4 rv[8], lv[8];
    scores(5, 6, rv);                 // right
    scores(3, 4, lv);                 // left
    put(0, grp_max(rv));
    put(1, grp_max(lv));
    __syncthreads();                  // B1
    const f32x4 MR = get_max(0), ML = get_max(1);
    f32x4 sR = {0.f, 0.f, 0.f, 0.f}, sL = {0.f, 0.f, 0.f, 0.f};
#pragma unroll
    for (int m = 0; m < 8; ++m) {
#pragma unroll
      for (int q = 0; q < 4; ++q) {
        rv[m][q] = expf(rv[m][q] - MR[q]);
        lv[m][q] = expf(lv[m][q] - ML[q]);
      }
      sR += rv[m];
      sL += lv[m];
    }
    put(2, grp_sum(sR));
    put(3, grp_sum(sL));
    __syncthreads();                // B2
    const f32x4 SR = get_sum(2), SL = get_sum(3);
    f32x4 iR, iL;
#pragma unroll
    for (int q = 0; q < 4; ++q) { iR[q] = 1.f / SR[q]; iL[q] = 1.f / SL[q]; }
#pragma unroll
    for (int m = 0; m < 8; ++m) { rv[m] *= iR; lv[m] *= iL; }
    scan(rv, 4);
    scan(lv, 5);
    __syncthreads();                // B3
    const f32x4 pR = get_pref(4), pL = get_pref(5);
#pragma unroll
    for (int m = 0; m < 8; ++m) { rv[m] += pR; lv[m] += pL; }
    // mask = af*(1-bfx) + (1-afx)*bf   (normalized totals == 1)
#pragma unroll
    for (int m = 7; m >= 0; --m) {
      f32x4 afx, bfx;
#pragma unroll
      for (int q = 0; q < 4; ++q) {
        const float ua = __shfl_up(lv[m][q], 1, 64);
        const float ub = __shfl_up(rv[m][q], 1, 64);
        const float la = (m > 0) ? __shfl(lv[m - 1][q], (lane & 48) | 15, 64) : pL[q];
        const float lb = (m > 0) ? __shfl(rv[m - 1][q], (lane & 48) | 15, 64) : pR[q];
        afx[q] = (c == 0) ? la : ua;
        bfx[q] = (c == 0) ? lb : ub;
      }
      lv[m] = lv[m] * (1.f - bfx) + (1.f - afx) * rv[m];
    }
    // spill mask to LDS (same lane re-reads it later; no barrier needed)
#pragma unroll
    for (int m = 0; m < 8; ++m)
#pragma unroll
      for (int q = 0; q < 4; ++q)
        sP[(4 * g2 + q) * STRP + sbase + 16 * m + c] = lv[m][q];
  }

  // ================= phase B: global (regs) + local*mask -> sP ============
  {
    f32x4 gv[8];
    scores(0, 1, gv);               // global
    put(0, grp_max(gv));
    __syncthreads();                // B4
    const f32x4 MG = get_max(0);
    f32x4 sG = {0.f, 0.f, 0.f, 0.f};
#pragma unroll
    for (int m = 0; m < 8; ++m) {
#pragma unroll
      for (int q = 0; q < 4; ++q) gv[m][q] = expf(gv[m][q] - MG[q]);
      sG += gv[m];
    }
    put(2, grp_sum(sG));
    __syncthreads();                // B5
    const f32x4 SG = get_sum(2);
    f32x4 iG;
#pragma unroll
    for (int q = 0; q < 4; ++q) iG[q] = 0.5f / SG[q];

    f32x4 ov[8];
    scores(7, 8, ov);               // local
    put(1, grp_max(ov));
    __syncthreads();                // B6
    const f32x4 MO = get_max(1);
    f32x4 sO = {0.f, 0.f, 0.f, 0.f};
#pragma unroll
    for (int m = 0; m < 8; ++m) {
#pragma unroll
      for (int q = 0; q < 4; ++q)
        ov[m][q] = expf(ov[m][q] - MO[q]) * sP[(4 * g2 + q) * STRP + sbase + 16 * m + c];
      sO += ov[m];
    }
    put(3, grp_sum(sO));
    __syncthreads();                // B7
    const f32x4 SO = get_sum(3);
    f32x4 iO;
#pragma unroll
    for (int q = 0; q < 4; ++q) iO[q] = 0.5f / SO[q];
#pragma unroll
    for (int m = 0; m < 8; ++m)
#pragma unroll
      for (int q = 0; q < 4; ++q)
        sP[(4 * g2 + q) * STRP + sbase + 16 * m + c] =
            gv[m][q] * iG[q] + ov[m][q] * iO[q];
  }
  __syncthreads();                  // B8: P complete

  // ================= PV via MFMA =================
  f32x4 cacc[4];
#pragma unroll
  for (int dt = 0; dt < 4; ++dt) cacc[dt] = (f32x4){0.f, 0.f, 0.f, 0.f};
  {
    const _Float16* vbh = Ph + mbase(2);
    const _Float16* vbl = Pl + mbase(2);
#pragma unroll
    for (int kk = 0; kk < 4; ++kk) {
      const int sk = sbase + kk * 32;
      const float* pp = sP + c * STRP + sk + 8 * g2;
      float pv[8];
      *(float4*)&pv[0] = *(const float4*)pp;
      *(float4*)&pv[4] = *(const float4*)(pp + 4);
      half8 pah, pal;
#pragma unroll
      for (int j = 0; j < 8; ++j) {
        const _Float16 h16 = (_Float16)pv[j];
        pah[j] = h16;
        pal[j] = (_Float16)(pv[j] - (float)h16);
      }
#pragma unroll
      for (int dt = 0; dt < 4; ++dt) {
        const _Float16* vh = vbh + (size_t)(dt * 16 + c) * 1024 + sk + 8 * g2;
        const _Float16* vl = vbl + (size_t)(dt * 16 + c) * 1024 + sk + 8 * g2;
        const half8 bh8 = *(const half8*)vh;
        const half8 bl8 = *(const half8*)vl;
        cacc[dt] = MFMA16(pah, bh8, cacc[dt]);
        cacc[dt] = MFMA16(pah, bl8, cacc[dt]);
        cacc[dt] = MFMA16(pal, bh8, cacc[dt]);
      }
    }
  }
  __syncthreads();                  // all P reads done before reuse
#pragma unroll
  for (int dt = 0; dt < 4; ++dt)
#pragma unroll
    for (int q = 0; q < 4; ++q)
      sP[(wave * 16 + 4 * g2 + q) * 65 + dt * 16 + c] = cacc[dt][q];
  __syncthreads();
  {
    const int b2 = bh >> 4, hh = bh & 15;
    for (int o = tid; o < 1024; o += 512) {
      const int r = o >> 6, d = o & 63;
      float a = 0.f;
#pragma unroll
      for (int w = 0; w < 8; ++w) a += sP[(w * 16 + r) * 65 + d];
      attnOut[((size_t)(t0 + r) * 4 + b2) * 1024 + hh * 64 + d] = a;
    }
  }
}

extern "C" void kernel_launch(void* const* d_in, const int* in_sizes, int n_in,
                              void* d_out, int out_size, void* d_ws, size_t ws_size,
                              hipStream_t stream) {
  const float* x     = (const float*)d_in[0];
  const float* w_in  = (const float*)d_in[1];
  const float* b_in  = (const float*)d_in[2];
  const float* w_out = (const float*)d_in[3];
  const float* b_out = (const float*)d_in[4];

  const size_t NP = (size_t)9 * 64 * 1024 * 64;
  _Float16* Ph = (_Float16*)d_ws;
  _Float16* Pl = Ph + NP;
  float* attn = (float*)(Pl + NP);

  (void)hipFuncSetAttribute((const void*)attn_mfma,
                            hipFuncAttributeMaxDynamicSharedMemorySize,
                            SMEM_ATTN);

  // proj = x @ w_in^T + b_in -> fp16 h/l split, head-major; v transposed
  gemm_mfma<1><<<dim3(32, 72), 256, 0, stream>>>(x, w_in, b_in, nullptr, Ph, Pl, 4096, 9216, 1024);
  // fused attention
  attn_mfma<<<dim3(64, 64), 512, SMEM_ATTN, stream>>>(Ph, Pl, attn);
  // out = attn @ w_out^T + b_out
  gemm_mfma<0><<<dim3(32, 8), 256, 0, stream>>>(attn, w_out, b_out, (float*)d_out, nullptr, nullptr, 4096, 1024, 1024);
}